// Round 4
// baseline (234.495 us; speedup 1.0000x reference)
//
#include <hip/hip_runtime.h>

#define ROWS 4096
#define NCOL 8192
#define THREADS 256
#define F4PT 8   // float4 per thread: 256*8*4 = 8192 elements

typedef float nfloat4 __attribute__((ext_vector_type(4)));  // native vec for nontemporal builtin

__global__ __launch_bounds__(THREADS, 4)
void sparsemax_kernel(const float* __restrict__ x, float* __restrict__ out) {
    __shared__ float srow[NCOL];     // the row, explicitly resident (32 KB)
    __shared__ float ssum[2][4];     // ping-pong per-wave partial sums
    __shared__ int   scnt[2][4];     // ping-pong per-wave partial counts
    __shared__ float smax[4];

    const int row = blockIdx.x;
    const size_t base = (size_t)row * NCOL;
    const float4* __restrict__ xr = (const float4*)(x + base);
    nfloat4* __restrict__ outr = (nfloat4*)(out + base);
    float4* __restrict__ sr4 = (float4*)srow;
    const int tid = threadIdx.x;
    const int wave = tid >> 6;
    const int lane = tid & 63;

    // ---- Pass 1: global -> LDS, fused block-max ----
    float m = -INFINITY;
#pragma unroll
    for (int j = 0; j < F4PT; ++j) {
        float4 q = xr[tid + THREADS * j];
        sr4[tid + THREADS * j] = q;
        m = fmaxf(m, fmaxf(fmaxf(q.x, q.y), fmaxf(q.z, q.w)));
    }
#pragma unroll
    for (int off = 32; off > 0; off >>= 1) {
        m = fmaxf(m, __shfl_down(m, off, 64));
    }
    if (lane == 0) smax[wave] = m;
    __syncthreads();
    float t = fmaxf(fmaxf(smax[0], smax[1]), fmaxf(smax[2], smax[3])) - 1.0f;

    // ---- Michelot fixed-point iteration, one barrier per iteration ----
    // timeline: write buf b, barrier, all threads read buf b; next iter writes
    // buf 1-b (no WAR: re-writes of buf b happen only after the NEXT barrier,
    // and all reads of buf b complete before that barrier is reached).
    int prev_k = -1;
    for (int it = 0; it < 32; ++it) {
        const int b = it & 1;
        float s = 0.0f;
        int   k = 0;
#pragma unroll
        for (int j = 0; j < F4PT; ++j) {
            float4 q = sr4[tid + THREADS * j];
            if (q.x > t) { s += q.x; ++k; }
            if (q.y > t) { s += q.y; ++k; }
            if (q.z > t) { s += q.z; ++k; }
            if (q.w > t) { s += q.w; ++k; }
        }
#pragma unroll
        for (int off = 32; off > 0; off >>= 1) {
            s += __shfl_down(s, off, 64);
            k += __shfl_down(k, off, 64);
        }
        if (lane == 0) { ssum[b][wave] = s; scnt[b][wave] = k; }
        __syncthreads();
        // every thread redundantly reduces the 4 partials (no tid==0 serialization)
        float st = ssum[b][0] + ssum[b][1] + ssum[b][2] + ssum[b][3];
        int   kt = scnt[b][0] + scnt[b][1] + scnt[b][2] + scnt[b][3];
        if (kt == prev_k) break;          // support stable => tau converged (exact)
        prev_k = kt;
        t = (st - 1.0f) / (float)kt;
    }

    // ---- Epilogue: out = max(x - tau, 0), nontemporal float4 stores ----
#pragma unroll
    for (int j = 0; j < F4PT; ++j) {
        float4 q = sr4[tid + THREADS * j];
        nfloat4 r;
        r.x = fmaxf(q.x - t, 0.0f);
        r.y = fmaxf(q.y - t, 0.0f);
        r.z = fmaxf(q.z - t, 0.0f);
        r.w = fmaxf(q.w - t, 0.0f);
        __builtin_nontemporal_store(r, &outr[tid + THREADS * j]);
    }
}

extern "C" void kernel_launch(void* const* d_in, const int* in_sizes, int n_in,
                              void* d_out, int out_size, void* d_ws, size_t ws_size,
                              hipStream_t stream) {
    const float* x = (const float*)d_in[0];
    float* out = (float*)d_out;
    sparsemax_kernel<<<ROWS, THREADS, 0, stream>>>(x, out);
}